// Round 1
// baseline (568.183 us; speedup 1.0000x reference)
//
#include <hip/hip_runtime.h>

typedef __bf16 bf16x8 __attribute__((ext_vector_type(8)));
typedef float  f32x4  __attribute__((ext_vector_type(4)));
typedef unsigned short u16x8 __attribute__((ext_vector_type(8)));
typedef unsigned short ushort_t;

#define NEGF (-1e20f)

__device__ __forceinline__ unsigned short f2bf(float f) {
  union { float f; unsigned u; } x; x.f = f;
  unsigned r = x.u + 0x7fffu + ((x.u >> 16) & 1u);
  return (unsigned short)(r >> 16);
}
__device__ __forceinline__ float bf2f(unsigned short h) {
  union { unsigned u; float f; } x; x.u = ((unsigned)h) << 16;
  return x.f;
}

__device__ __forceinline__ void gl16(const void* g, void* l) {
  __builtin_amdgcn_global_load_lds(
      (const __attribute__((address_space(1))) unsigned int*)g,
      (__attribute__((address_space(3))) unsigned int*)l, 16, 0, 0);
}

// ---------------- f32 -> bf16 convert (8 elems/thread) ----------------
__global__ __launch_bounds__(256) void k_cvt(const float* __restrict__ in,
                                             unsigned short* __restrict__ out) {
  size_t i = ((size_t)blockIdx.x * 256 + threadIdx.x) * 8;
  const float4* p = (const float4*)(in + i);
  float4 a = p[0], b = p[1];
  u16x8 o;
  o[0] = f2bf(a.x); o[1] = f2bf(a.y); o[2] = f2bf(a.z); o[3] = f2bf(a.w);
  o[4] = f2bf(b.x); o[5] = f2bf(b.y); o[6] = f2bf(b.z); o[7] = f2bf(b.w);
  *(u16x8*)(out + i) = o;
}

// ---------------- W (1024x1024 f32) -> W^T bf16 ----------------
__global__ __launch_bounds__(256) void k_cvt_w(const float* __restrict__ W,
                                               unsigned short* __restrict__ WT) {
  __shared__ float t[32][33];
  const int tid = threadIdx.x;
  const int tx = tid & 31, ty = tid >> 5;           // ty 0..7
  const int e0 = blockIdx.y * 32, a0 = blockIdx.x * 32;
#pragma unroll
  for (int i = 0; i < 4; i++) {
    int el = ty + i * 8;
    t[el][tx] = W[(size_t)(e0 + el) * 1024 + a0 + tx];
  }
  __syncthreads();
#pragma unroll
  for (int i = 0; i < 4; i++) {
    int al = ty + i * 8;
    WT[(size_t)(a0 + al) * 1024 + e0 + tx] = f2bf(t[tx][al]);
  }
}

// ---------------- generic bf16 MFMA GEMM: C = A[M][K] x Bt[N][K]^T ----
// MODE 0: bf16 out with scale (projections)
// MODE 1: scores epilogue, bf16 store
// MODE 2: scores epilogue, f32 store
// MODE 3: PV, f32 out, K = brow+128 (causal truncation)
template<int MODE>
__global__ __launch_bounds__(256) void k_gemm(
    const unsigned short* __restrict__ A, int lda, size_t batchA,
    const unsigned short* __restrict__ Bt, int ldb, size_t batchB,
    void* __restrict__ Cv, int ldc, size_t batchC,
    int K, float scale, const int* __restrict__ mask)
{
  const int bx = blockIdx.x, by = blockIdx.y, b = blockIdx.z;
  if ((MODE == 1 || MODE == 2) && bx > by) return;   // strictly above diagonal
  const int brow = by * 128, bcol = bx * 128;
  A  += (size_t)b * batchA;
  Bt += (size_t)b * batchB;

  __shared__ unsigned short As[128 * 32];
  __shared__ unsigned short Bs[128 * 32];

  const int tid = threadIdx.x, wid = tid >> 6, lane = tid & 63;
  const int wr = wid >> 1, wc = wid & 1;
  const int fr = lane & 15, fq = lane >> 4;

  f32x4 acc[4][4] = {};

  const int Keff = (MODE == 3) ? (brow + 128) : K;
  const int srow = wid * 16 + (lane >> 2);   // staging row within 64-row half
  const int scol = (lane & 3) * 8;           // staging col (elements)

  for (int k0 = 0; k0 < Keff; k0 += 32) {
    const unsigned short* ga = A + (size_t)(brow + srow) * lda + k0 + scol;
    gl16(ga, &As[(wid * 16) * 32]);
    gl16(ga + (size_t)64 * lda, &As[(64 + wid * 16) * 32]);
    const unsigned short* gb = Bt + (size_t)(bcol + srow) * ldb + k0 + scol;
    gl16(gb, &Bs[(wid * 16) * 32]);
    gl16(gb + (size_t)64 * ldb, &Bs[(64 + wid * 16) * 32]);
    __syncthreads();

    bf16x8 af[4], bfv[4];
#pragma unroll
    for (int m = 0; m < 4; m++)
      af[m] = __builtin_bit_cast(bf16x8,
          *(const u16x8*)&As[(wr * 64 + m * 16 + fr) * 32 + fq * 8]);
#pragma unroll
    for (int n = 0; n < 4; n++)
      bfv[n] = __builtin_bit_cast(bf16x8,
          *(const u16x8*)&Bs[(wc * 64 + n * 16 + fr) * 32 + fq * 8]);
#pragma unroll
    for (int m = 0; m < 4; m++)
#pragma unroll
      for (int n = 0; n < 4; n++)
        acc[m][n] = __builtin_amdgcn_mfma_f32_16x16x32_bf16(af[m], bfv[n], acc[m][n], 0, 0, 0);
    __syncthreads();
  }

  if (MODE == 0) {
    unsigned short* C = (unsigned short*)Cv;
#pragma unroll
    for (int m = 0; m < 4; m++)
#pragma unroll
      for (int n = 0; n < 4; n++)
#pragma unroll
        for (int r = 0; r < 4; r++) {
          int rg = brow + wr * 64 + m * 16 + fq * 4 + r;
          int cg = bcol + wc * 64 + n * 16 + fr;
          C[(size_t)rg * ldc + cg] = f2bf(acc[m][n][r] * scale);
        }
  } else if (MODE == 1 || MODE == 2) {
    const int* mk = mask + (size_t)b * 2048 * 2048;
    unsigned short* Cb = (unsigned short*)Cv + (size_t)b * batchC;
    float* Cf = (float*)Cv + (size_t)b * batchC;
#pragma unroll
    for (int m = 0; m < 4; m++)
#pragma unroll
      for (int n = 0; n < 4; n++)
#pragma unroll
        for (int r = 0; r < 4; r++) {
          int q = brow + wr * 64 + m * 16 + fq * 4 + r;
          int kk = bcol + wc * 64 + n * 16 + fr;
          float s = acc[m][n][r];
          if (mk[(size_t)q * 2048 + kk] == 0) s = NEGF;
          if (kk > q) s = NEGF;
          else if (s == 0.0f) s = NEGF;
          if (MODE == 2) Cf[(size_t)q * ldc + kk] = s;
          else           Cb[(size_t)q * ldc + kk] = f2bf(s);
        }
  } else {
    float* C = (float*)Cv + (size_t)b * batchC;
#pragma unroll
    for (int m = 0; m < 4; m++)
#pragma unroll
      for (int n = 0; n < 4; n++)
#pragma unroll
        for (int r = 0; r < 4; r++) {
          int rg = brow + wr * 64 + m * 16 + fq * 4 + r;
          int cg = bcol + wc * 64 + n * 16 + fr;
          C[(size_t)rg * ldc + cg] = acc[m][n][r];
        }
  }
}

// ---------------- row softmax (one block per row) ----------------
template<bool F32IN>
__global__ __launch_bounds__(256) void k_softmax(const void* __restrict__ Sin,
                                                 unsigned short* __restrict__ P) {
  const int row = blockIdx.x;
  const int qq = row & 2047;
  const int L = ((qq >> 7) + 1) << 7;   // causal tile-rounded row length
  const int tid = threadIdx.x;
  float val[8];
  float mx = -3.0e38f;
  int cnt = 0;
  if (F32IN) {
    const float* s = (const float*)Sin + (size_t)row * 2048;
    for (int i = tid; i < L; i += 256) { float f = s[i]; val[cnt++] = f; mx = fmaxf(mx, f); }
  } else {
    const unsigned short* s = (const unsigned short*)Sin + (size_t)row * 2048;
    for (int i = tid; i < L; i += 256) { float f = bf2f(s[i]); val[cnt++] = f; mx = fmaxf(mx, f); }
  }
#pragma unroll
  for (int o = 32; o; o >>= 1) mx = fmaxf(mx, __shfl_xor(mx, o));
  __shared__ float sred[8];
  if ((tid & 63) == 0) sred[tid >> 6] = mx;
  __syncthreads();
  mx = fmaxf(fmaxf(sred[0], sred[1]), fmaxf(sred[2], sred[3]));
  float sum = 0.f;
  for (int j = 0; j < cnt; j++) { val[j] = __expf(val[j] - mx); sum += val[j]; }
#pragma unroll
  for (int o = 32; o; o >>= 1) sum += __shfl_xor(sum, o);
  if ((tid & 63) == 0) sred[4 + (tid >> 6)] = sum;
  __syncthreads();
  sum = (sred[4] + sred[5]) + (sred[6] + sred[7]);
  const float inv = 1.0f / sum;
  unsigned short* p = P + (size_t)row * 2048;
  int j = 0;
  for (int i = tid; i < L; i += 256) p[i] = f2bf(val[j++] * inv);
}

extern "C" void kernel_launch(void* const* d_in, const int* in_sizes, int n_in,
                              void* d_out, int out_size, void* d_ws, size_t ws_size,
                              hipStream_t stream) {
  const float* q   = (const float*)d_in[0];
  const float* k   = (const float*)d_in[1];
  const float* v   = (const float*)d_in[2];
  const int*   msk = (const int*)d_in[3];
  const float* Wq  = (const float*)d_in[4];
  const float* Wk  = (const float*)d_in[5];
  const float* Wv  = (const float*)d_in[6];
  float* out = (float*)d_out;

  char* ws = (char*)d_ws;
  unsigned short* WqT = (unsigned short*)(ws + 0);
  unsigned short* WkT = (unsigned short*)(ws + 2097152);
  unsigned short* WvT = (unsigned short*)(ws + 4194304);
  unsigned short* qp  = (unsigned short*)(ws + 6291456);
  unsigned short* kp  = (unsigned short*)(ws + 39845888);
  unsigned short* vpT = (unsigned short*)(ws + 73400320);
  unsigned short* qbf = (unsigned short*)(ws + 106954752);
  unsigned short* kbf = (unsigned short*)(ws + 140509184);
  unsigned short* vbf = (unsigned short*)(ws + 174063616);
  // f32-scores path needs 308,281,344 bytes; bf16 path needs 207,618,048.
  const bool f32s = ws_size >= 308281344ull;
  float* Sf = (float*)(ws + 106954752);                    // aliases q/k/v bf16 (dead)
  unsigned short* P = f32s ? (unsigned short*)(ws + 241172480)
                           : (unsigned short*)(ws + 106954752);

  dim3 blk(256);
  // 1) conversions
  k_cvt<<<dim3(8192), blk, 0, stream>>>(q, qbf);
  k_cvt<<<dim3(8192), blk, 0, stream>>>(k, kbf);
  k_cvt<<<dim3(8192), blk, 0, stream>>>(v, vbf);
  k_cvt_w<<<dim3(32, 32), blk, 0, stream>>>(Wq, WqT);
  k_cvt_w<<<dim3(32, 32), blk, 0, stream>>>(Wk, WkT);
  k_cvt_w<<<dim3(32, 32), blk, 0, stream>>>(Wv, WvT);

  // 2) projections: qp (scale folded 1/sqrt(1024)), kp, vpT
  k_gemm<0><<<dim3(8, 128, 1), blk, 0, stream>>>(qbf, 1024, 0, WqT, 1024, 0,
                                                 qp, 1024, 0, 1024, 0.03125f, nullptr);
  k_gemm<0><<<dim3(8, 128, 1), blk, 0, stream>>>(kbf, 1024, 0, WkT, 1024, 0,
                                                 kp, 1024, 0, 1024, 1.0f, nullptr);
  k_gemm<0><<<dim3(128, 8, 1), blk, 0, stream>>>(WvT, 1024, 0, vbf, 1024, 0,
                                                 vpT, 16384, 0, 1024, 1.0f, nullptr);

  // 3) scores (causal lower-triangle tiles only)
  if (f32s)
    k_gemm<2><<<dim3(16, 16, 8), blk, 0, stream>>>(qp, 1024, (size_t)2048 * 1024,
                                                   kp, 1024, (size_t)2048 * 1024,
                                                   Sf, 2048, (size_t)2048 * 2048,
                                                   1024, 1.0f, msk);
  else
    k_gemm<1><<<dim3(16, 16, 8), blk, 0, stream>>>(qp, 1024, (size_t)2048 * 1024,
                                                   kp, 1024, (size_t)2048 * 1024,
                                                   P, 2048, (size_t)2048 * 2048,
                                                   1024, 1.0f, msk);

  // 4) softmax
  if (f32s) k_softmax<true><<<dim3(16384), blk, 0, stream>>>(Sf, P);
  else      k_softmax<false><<<dim3(16384), blk, 0, stream>>>(P, P);

  // 5) PV: out = P x vpT^T, K truncated at diagonal
  k_gemm<3><<<dim3(8, 16, 8), blk, 0, stream>>>(P, 2048, (size_t)2048 * 2048,
                                                vpT, 16384, (size_t)2048,
                                                out, 1024, (size_t)2048 * 1024,
                                                0, 1.0f, nullptr);
  (void)in_sizes; (void)n_in; (void)out_size;
}

// Round 2
// 517.532 us; speedup vs baseline: 1.0979x; 1.0979x over previous
//
#include <hip/hip_runtime.h>
#include <math.h>

typedef __bf16 bf16x8 __attribute__((ext_vector_type(8)));
typedef float  f32x4  __attribute__((ext_vector_type(4)));
typedef unsigned short u16x8 __attribute__((ext_vector_type(8)));

#define NEGF (-1e20f)

__device__ __forceinline__ unsigned short f2bf(float f) {
  union { float f; unsigned u; } x; x.f = f;
  unsigned r = x.u + 0x7fffu + ((x.u >> 16) & 1u);
  return (unsigned short)(r >> 16);
}
__device__ __forceinline__ float bf2f(unsigned short h) {
  union { unsigned u; float f; } x; x.u = ((unsigned)h) << 16;
  return x.f;
}

__device__ __forceinline__ void gl16(const void* g, void* l) {
  __builtin_amdgcn_global_load_lds(
      (const __attribute__((address_space(1))) unsigned int*)g,
      (__attribute__((address_space(3))) unsigned int*)l, 16, 0, 0);
}

// ---------------- f32 -> bf16 convert (8 elems/thread) ----------------
__global__ __launch_bounds__(256) void k_cvt(const float* __restrict__ in,
                                             unsigned short* __restrict__ out) {
  size_t i = ((size_t)blockIdx.x * 256 + threadIdx.x) * 8;
  const float4* p = (const float4*)(in + i);
  float4 a = p[0], b = p[1];
  u16x8 o;
  o[0] = f2bf(a.x); o[1] = f2bf(a.y); o[2] = f2bf(a.z); o[3] = f2bf(a.w);
  o[4] = f2bf(b.x); o[5] = f2bf(b.y); o[6] = f2bf(b.z); o[7] = f2bf(b.w);
  *(u16x8*)(out + i) = o;
}

// ---------------- W (1024x1024 f32) -> W^T bf16 ----------------
__global__ __launch_bounds__(256) void k_cvt_w(const float* __restrict__ W,
                                               unsigned short* __restrict__ WT) {
  __shared__ float t[32][33];
  const int tid = threadIdx.x;
  const int tx = tid & 31, ty = tid >> 5;
  const int e0 = blockIdx.y * 32, a0 = blockIdx.x * 32;
#pragma unroll
  for (int i = 0; i < 4; i++) {
    int el = ty + i * 8;
    t[el][tx] = W[(size_t)(e0 + el) * 1024 + a0 + tx];
  }
  __syncthreads();
#pragma unroll
  for (int i = 0; i < 4; i++) {
    int al = ty + i * 8;
    WT[(size_t)(a0 + al) * 1024 + e0 + tx] = f2bf(t[tx][al]);
  }
}

// ---------------- generic bf16 MFMA GEMM: C = A[M][K] x Bt[N][K]^T ----
// MODE 0: bf16 out with scale (projections)
// MODE 3: PV, f32 out, K = brow+128 (causal truncation), by reversed
template<int MODE>
__global__ __launch_bounds__(256) void k_gemm(
    const unsigned short* __restrict__ A, int lda, size_t batchA,
    const unsigned short* __restrict__ Bt, int ldb, size_t batchB,
    void* __restrict__ Cv, int ldc, size_t batchC,
    int K, float scale)
{
  const int bx = blockIdx.x, b = blockIdx.z;
  const int by = (MODE == 3) ? (int)(gridDim.y - 1 - blockIdx.y) : (int)blockIdx.y;
  const int brow = by * 128, bcol = bx * 128;
  A  += (size_t)b * batchA;
  Bt += (size_t)b * batchB;

  __shared__ unsigned short As[128 * 32];
  __shared__ unsigned short Bs[128 * 32];

  const int tid = threadIdx.x, wid = tid >> 6, lane = tid & 63;
  const int wr = wid >> 1, wc = wid & 1;
  const int fr = lane & 15, fq = lane >> 4;

  f32x4 acc[4][4] = {};

  const int Keff = (MODE == 3) ? (brow + 128) : K;
  const int srow = wid * 16 + (lane >> 2);
  const int scol = (lane & 3) * 8;

  for (int k0 = 0; k0 < Keff; k0 += 32) {
    const unsigned short* ga = A + (size_t)(brow + srow) * lda + k0 + scol;
    gl16(ga, &As[(wid * 16) * 32]);
    gl16(ga + (size_t)64 * lda, &As[(64 + wid * 16) * 32]);
    const unsigned short* gb = Bt + (size_t)(bcol + srow) * ldb + k0 + scol;
    gl16(gb, &Bs[(wid * 16) * 32]);
    gl16(gb + (size_t)64 * ldb, &Bs[(64 + wid * 16) * 32]);
    __syncthreads();

    bf16x8 af[4], bfv[4];
#pragma unroll
    for (int m = 0; m < 4; m++)
      af[m] = __builtin_bit_cast(bf16x8,
          *(const u16x8*)&As[(wr * 64 + m * 16 + fr) * 32 + fq * 8]);
#pragma unroll
    for (int n = 0; n < 4; n++)
      bfv[n] = __builtin_bit_cast(bf16x8,
          *(const u16x8*)&Bs[(wc * 64 + n * 16 + fr) * 32 + fq * 8]);
#pragma unroll
    for (int m = 0; m < 4; m++)
#pragma unroll
      for (int n = 0; n < 4; n++)
        acc[m][n] = __builtin_amdgcn_mfma_f32_16x16x32_bf16(af[m], bfv[n], acc[m][n], 0, 0, 0);
    __syncthreads();
  }

  if (MODE == 0) {
    unsigned short* C = (unsigned short*)Cv;
#pragma unroll
    for (int m = 0; m < 4; m++)
#pragma unroll
      for (int n = 0; n < 4; n++)
#pragma unroll
        for (int r = 0; r < 4; r++) {
          int rg = brow + wr * 64 + m * 16 + fq * 4 + r;
          int cg = bcol + wc * 64 + n * 16 + fr;
          C[(size_t)rg * ldc + cg] = f2bf(acc[m][n][r] * scale);
        }
  } else {
    float* C = (float*)Cv + (size_t)b * batchC;
#pragma unroll
    for (int m = 0; m < 4; m++)
#pragma unroll
      for (int n = 0; n < 4; n++)
#pragma unroll
        for (int r = 0; r < 4; r++) {
          int rg = brow + wr * 64 + m * 16 + fq * 4 + r;
          int cg = bcol + wc * 64 + n * 16 + fr;
          C[(size_t)rg * ldc + cg] = acc[m][n][r];
        }
  }
}

// ---------------- scores: compact causal grid + mask bit-prefetch ------
// grid: 1088 blocks (8 batches x 136 lower-triangle 128x128 tiles), XCD-swizzled
template<int F32OUT>
__global__ __launch_bounds__(256) void k_scores(
    const unsigned short* __restrict__ QP,
    const unsigned short* __restrict__ KP,
    void* __restrict__ Sv,
    const int* __restrict__ mask)
{
  int bid0 = blockIdx.x;
  int bid = (bid0 & 7) * 136 + (bid0 >> 3);   // 1088 % 8 == 0: bijective
  const int b = bid / 136;
  int t = bid - b * 136;
  int by = (int)((sqrtf((float)(8 * t + 1)) - 1.0f) * 0.5f);
  if ((by + 1) * (by + 2) / 2 <= t) by++;
  else if (by * (by + 1) / 2 > t) by--;
  const int bx = t - (by * (by + 1)) / 2;     // bx <= by
  const int brow = by * 128, bcol = bx * 128;

  const unsigned short* A  = QP + (size_t)b * (2048 * 1024);
  const unsigned short* Bt = KP + (size_t)b * (2048 * 1024);

  __shared__ unsigned short As[128 * 32];
  __shared__ unsigned short Bs[128 * 32];

  const int tid = threadIdx.x, wid = tid >> 6, lane = tid & 63;
  const int wr = wid >> 1, wc = wid & 1;
  const int fr = lane & 15, fq = lane >> 4;

  // --- mask prefetch: the 64 elements this lane's epilogue needs -> 64 bits
  const int* mk = mask + (size_t)b * 2048 * 2048;
  unsigned mbits[2];
#pragma unroll
  for (int h = 0; h < 2; h++) {
    int tmp[32];
#pragma unroll
    for (int j = 0; j < 32; j++) {
      int jj = h * 32 + j;
      int m = jj >> 4, n = (jj >> 2) & 3, r = jj & 3;
      int qq = brow + wr * 64 + m * 16 + fq * 4 + r;
      int kk = bcol + wc * 64 + n * 16 + fr;
      tmp[j] = mk[(size_t)qq * 2048 + kk];
    }
    unsigned bv = 0;
#pragma unroll
    for (int j = 0; j < 32; j++) bv |= (tmp[j] ? 1u : 0u) << j;
    mbits[h] = bv;
  }

  f32x4 acc[4][4] = {};
  const int srow = wid * 16 + (lane >> 2);
  const int scol = (lane & 3) * 8;

  for (int k0 = 0; k0 < 1024; k0 += 32) {
    const unsigned short* ga = A + (size_t)(brow + srow) * 1024 + k0 + scol;
    gl16(ga, &As[(wid * 16) * 32]);
    gl16(ga + (size_t)64 * 1024, &As[(64 + wid * 16) * 32]);
    const unsigned short* gb = Bt + (size_t)(bcol + srow) * 1024 + k0 + scol;
    gl16(gb, &Bs[(wid * 16) * 32]);
    gl16(gb + (size_t)64 * 1024, &Bs[(64 + wid * 16) * 32]);
    __syncthreads();

    bf16x8 af[4], bfv[4];
#pragma unroll
    for (int m = 0; m < 4; m++)
      af[m] = __builtin_bit_cast(bf16x8,
          *(const u16x8*)&As[(wr * 64 + m * 16 + fr) * 32 + fq * 8]);
#pragma unroll
    for (int n = 0; n < 4; n++)
      bfv[n] = __builtin_bit_cast(bf16x8,
          *(const u16x8*)&Bs[(wc * 64 + n * 16 + fr) * 32 + fq * 8]);
#pragma unroll
    for (int m = 0; m < 4; m++)
#pragma unroll
      for (int n = 0; n < 4; n++)
        acc[m][n] = __builtin_amdgcn_mfma_f32_16x16x32_bf16(af[m], bfv[n], acc[m][n], 0, 0, 0);
    __syncthreads();
  }

  float* Cf = (float*)Sv + (size_t)b * 2048 * 2048;
  unsigned short* Cb = (unsigned short*)Sv + (size_t)b * 2048 * 2048;
#pragma unroll
  for (int m = 0; m < 4; m++)
#pragma unroll
    for (int n = 0; n < 4; n++)
#pragma unroll
      for (int r = 0; r < 4; r++) {
        int jj = (m << 4) | (n << 2) | r;
        int qq = brow + wr * 64 + m * 16 + fq * 4 + r;
        int kk = bcol + wc * 64 + n * 16 + fr;
        float s = acc[m][n][r];
        if (!((mbits[jj >> 5] >> (jj & 31)) & 1u)) s = NEGF;
        if (kk > qq) s = NEGF;
        else if (s == 0.0f) s = NEGF;
        if (F32OUT) Cf[(size_t)qq * 2048 + kk] = s;
        else        Cb[(size_t)qq * 2048 + kk] = f2bf(s);
      }
}

// ---------------- row softmax (one block per row) ----------------
template<bool F32IN>
__global__ __launch_bounds__(256) void k_softmax(const void* __restrict__ Sin,
                                                 unsigned short* __restrict__ P) {
  const int row = blockIdx.x;
  const int qq = row & 2047;
  const int L = ((qq >> 7) + 1) << 7;   // causal tile-rounded row length
  const int tid = threadIdx.x;
  float val[8];
  float mx = -3.0e38f;
  int cnt = 0;
  if (F32IN) {
    const float4* s = (const float4*)((const float*)Sin + (size_t)row * 2048);
    for (int i = tid; i * 4 < L; i += 256) {
      float4 f = s[i];
      val[cnt] = f.x; val[cnt + 1] = f.y; val[cnt + 2] = f.z; val[cnt + 3] = f.w;
      mx = fmaxf(fmaxf(fmaxf(mx, f.x), f.y), fmaxf(f.z, f.w));
      cnt += 4;
    }
  } else {
    const unsigned short* s = (const unsigned short*)Sin + (size_t)row * 2048;
    for (int i = tid; i < L; i += 256) { float f = bf2f(s[i]); val[cnt++] = f; mx = fmaxf(mx, f); }
  }
#pragma unroll
  for (int o = 32; o; o >>= 1) mx = fmaxf(mx, __shfl_xor(mx, o));
  __shared__ float sred[8];
  if ((tid & 63) == 0) sred[tid >> 6] = mx;
  __syncthreads();
  mx = fmaxf(fmaxf(sred[0], sred[1]), fmaxf(sred[2], sred[3]));
  float sum = 0.f;
  for (int j = 0; j < cnt; j++) { val[j] = __expf(val[j] - mx); sum += val[j]; }
#pragma unroll
  for (int o = 32; o; o >>= 1) sum += __shfl_xor(sum, o);
  if ((tid & 63) == 0) sred[4 + (tid >> 6)] = sum;
  __syncthreads();
  sum = (sred[4] + sred[5]) + (sred[6] + sred[7]);
  const float inv = 1.0f / sum;
  unsigned short* p = P + (size_t)row * 2048;
  if (F32IN) {
    int j = 0;
    for (int i = tid; i * 4 < L; i += 256) {
      ushort4 o;
      o.x = f2bf(val[j] * inv); o.y = f2bf(val[j + 1] * inv);
      o.z = f2bf(val[j + 2] * inv); o.w = f2bf(val[j + 3] * inv);
      *(ushort4*)(p + i * 4) = o;
      j += 4;
    }
  } else {
    int j = 0;
    for (int i = tid; i < L; i += 256) p[i] = f2bf(val[j++] * inv);
  }
}

extern "C" void kernel_launch(void* const* d_in, const int* in_sizes, int n_in,
                              void* d_out, int out_size, void* d_ws, size_t ws_size,
                              hipStream_t stream) {
  const float* q   = (const float*)d_in[0];
  const float* k   = (const float*)d_in[1];
  const float* v   = (const float*)d_in[2];
  const int*   msk = (const int*)d_in[3];
  const float* Wq  = (const float*)d_in[4];
  const float* Wk  = (const float*)d_in[5];
  const float* Wv  = (const float*)d_in[6];
  float* out = (float*)d_out;

  char* ws = (char*)d_ws;
  unsigned short* WqT = (unsigned short*)(ws + 0);
  unsigned short* WkT = (unsigned short*)(ws + 2097152);
  unsigned short* WvT = (unsigned short*)(ws + 4194304);
  unsigned short* qp  = (unsigned short*)(ws + 6291456);
  unsigned short* kp  = (unsigned short*)(ws + 39845888);
  unsigned short* vpT = (unsigned short*)(ws + 73400320);
  unsigned short* qbf = (unsigned short*)(ws + 106954752);
  unsigned short* kbf = (unsigned short*)(ws + 140509184);
  unsigned short* vbf = (unsigned short*)(ws + 174063616);
  const bool f32s = ws_size >= 308281344ull;
  float* Sf = (float*)(ws + 106954752);                    // aliases q/k/v bf16 (dead)
  unsigned short* P = f32s ? (unsigned short*)(ws + 241172480)
                           : (unsigned short*)(ws + 106954752);

  dim3 blk(256);
  // 1) conversions
  k_cvt<<<dim3(8192), blk, 0, stream>>>(q, qbf);
  k_cvt<<<dim3(8192), blk, 0, stream>>>(k, kbf);
  k_cvt<<<dim3(8192), blk, 0, stream>>>(v, vbf);
  k_cvt_w<<<dim3(32, 32), blk, 0, stream>>>(Wq, WqT);
  k_cvt_w<<<dim3(32, 32), blk, 0, stream>>>(Wk, WkT);
  k_cvt_w<<<dim3(32, 32), blk, 0, stream>>>(Wv, WvT);

  // 2) projections: qp (scale folded 1/sqrt(1024)), kp, vpT
  k_gemm<0><<<dim3(8, 128, 1), blk, 0, stream>>>(qbf, 1024, 0, WqT, 1024, 0,
                                                 qp, 1024, 0, 1024, 0.03125f);
  k_gemm<0><<<dim3(8, 128, 1), blk, 0, stream>>>(kbf, 1024, 0, WkT, 1024, 0,
                                                 kp, 1024, 0, 1024, 1.0f);
  k_gemm<0><<<dim3(128, 8, 1), blk, 0, stream>>>(WvT, 1024, 0, vbf, 1024, 0,
                                                 vpT, 16384, 0, 1024, 1.0f);

  // 3) scores (compact causal grid, mask prefetched to bits)
  if (f32s)
    k_scores<1><<<dim3(1088), blk, 0, stream>>>(qp, kp, Sf, msk);
  else
    k_scores<0><<<dim3(1088), blk, 0, stream>>>(qp, kp, P, msk);

  // 4) softmax
  if (f32s) k_softmax<true><<<dim3(16384), blk, 0, stream>>>(Sf, P);
  else      k_softmax<false><<<dim3(16384), blk, 0, stream>>>(P, P);

  // 5) PV: out = P x vpT^T, K truncated at diagonal (long blocks first)
  k_gemm<3><<<dim3(8, 16, 8), blk, 0, stream>>>(P, 2048, (size_t)2048 * 2048,
                                                vpT, 16384, (size_t)2048,
                                                out, 1024, (size_t)2048 * 1024,
                                                0, 1.0f);
  (void)in_sizes; (void)n_in; (void)out_size;
}

// Round 3
// 479.641 us; speedup vs baseline: 1.1846x; 1.0790x over previous
//
#include <hip/hip_runtime.h>
#include <math.h>

typedef __bf16 bf16x8 __attribute__((ext_vector_type(8)));
typedef float  f32x4  __attribute__((ext_vector_type(4)));
typedef unsigned short u16x8 __attribute__((ext_vector_type(8)));

#define NEGF (-1e20f)

__device__ __forceinline__ unsigned short f2bf(float f) {
  union { float f; unsigned u; } x; x.f = f;
  unsigned r = x.u + 0x7fffu + ((x.u >> 16) & 1u);
  return (unsigned short)(r >> 16);
}
__device__ __forceinline__ float bf2f(unsigned short h) {
  union { unsigned u; float f; } x; x.u = ((unsigned)h) << 16;
  return x.f;
}

__device__ __forceinline__ void gl16(const void* g, void* l) {
  __builtin_amdgcn_global_load_lds(
      (const __attribute__((address_space(1))) unsigned int*)g,
      (__attribute__((address_space(3))) unsigned int*)l, 16, 0, 0);
}

// ---------------- f32 -> bf16 convert (8 elems/thread) ----------------
__global__ __launch_bounds__(256) void k_cvt(const float* __restrict__ in,
                                             unsigned short* __restrict__ out) {
  size_t i = ((size_t)blockIdx.x * 256 + threadIdx.x) * 8;
  const float4* p = (const float4*)(in + i);
  float4 a = p[0], b = p[1];
  u16x8 o;
  o[0] = f2bf(a.x); o[1] = f2bf(a.y); o[2] = f2bf(a.z); o[3] = f2bf(a.w);
  o[4] = f2bf(b.x); o[5] = f2bf(b.y); o[6] = f2bf(b.z); o[7] = f2bf(b.w);
  *(u16x8*)(out + i) = o;
}

// ---------------- W (1024x1024 f32) -> W^T bf16 ----------------
__global__ __launch_bounds__(256) void k_cvt_w(const float* __restrict__ W,
                                               unsigned short* __restrict__ WT) {
  __shared__ float t[32][33];
  const int tid = threadIdx.x;
  const int tx = tid & 31, ty = tid >> 5;
  const int e0 = blockIdx.y * 32, a0 = blockIdx.x * 32;
#pragma unroll
  for (int i = 0; i < 4; i++) {
    int el = ty + i * 8;
    t[el][tx] = W[(size_t)(e0 + el) * 1024 + a0 + tx];
  }
  __syncthreads();
#pragma unroll
  for (int i = 0; i < 4; i++) {
    int al = ty + i * 8;
    WT[(size_t)(a0 + al) * 1024 + e0 + tx] = f2bf(t[tx][al]);
  }
}

// ---------------- generic bf16 MFMA GEMM: C = A[M][K] x Bt[N][K]^T ----
// 2-phase pipelined (double-buffered LDS, prefetch t+1 before compute t).
// MODE 0: bf16 out with scale (projections), XCD-swizzled grid
// MODE 3: PV, f32 out, K = brow+128 (causal truncation), by reversed
template<int MODE>
__global__ __launch_bounds__(256) void k_gemm(
    const unsigned short* __restrict__ A, int lda, size_t batchA,
    const unsigned short* __restrict__ Bt, int ldb, size_t batchB,
    void* __restrict__ Cv, int ldc, size_t batchC,
    int K, float scale)
{
  int bx, by;
  const int b = blockIdx.z;
  if (MODE == 0) {
    // bijective XCD swizzle over the 2D grid (nwg % 8 == 0)
    int nwg = gridDim.x * gridDim.y;
    int lin = blockIdx.y * gridDim.x + blockIdx.x;
    int chunk = nwg >> 3;
    int swz = (lin & 7) * chunk + (lin >> 3);
    bx = swz % gridDim.x;
    by = swz / gridDim.x;
  } else {
    bx = blockIdx.x;
    by = (int)(gridDim.y - 1 - blockIdx.y);   // long K first
  }
  const int brow = by * 128, bcol = bx * 128;
  A  += (size_t)b * batchA;
  Bt += (size_t)b * batchB;

  __shared__ unsigned short As[2][128 * 32];
  __shared__ unsigned short Bs[2][128 * 32];

  const int tid = threadIdx.x, wid = tid >> 6, lane = tid & 63;
  const int wr = wid >> 1, wc = wid & 1;
  const int fr = lane & 15, fq = lane >> 4;

  f32x4 acc[4][4] = {};

  const int Keff = (MODE == 3) ? (brow + 128) : K;
  const int nt = Keff >> 5;
  const int srow = wid * 16 + (lane >> 2);
  const int scol = (lane & 3) * 8;

  auto stage = [&](int buf, int k0) {
    const unsigned short* ga = A + (size_t)(brow + srow) * lda + k0 + scol;
    gl16(ga, &As[buf][(wid * 16) * 32]);
    gl16(ga + (size_t)64 * lda, &As[buf][(64 + wid * 16) * 32]);
    const unsigned short* gb = Bt + (size_t)(bcol + srow) * ldb + k0 + scol;
    gl16(gb, &Bs[buf][(wid * 16) * 32]);
    gl16(gb + (size_t)64 * ldb, &Bs[buf][(64 + wid * 16) * 32]);
  };

  stage(0, 0);
  __syncthreads();
  int cur = 0;
  for (int t = 0; t < nt; ++t) {
    if (t + 1 < nt) stage(cur ^ 1, (t + 1) * 32);

    bf16x8 af[4], bfv[4];
#pragma unroll
    for (int m = 0; m < 4; m++)
      af[m] = __builtin_bit_cast(bf16x8,
          *(const u16x8*)&As[cur][(wr * 64 + m * 16 + fr) * 32 + fq * 8]);
#pragma unroll
    for (int n = 0; n < 4; n++)
      bfv[n] = __builtin_bit_cast(bf16x8,
          *(const u16x8*)&Bs[cur][(wc * 64 + n * 16 + fr) * 32 + fq * 8]);
#pragma unroll
    for (int m = 0; m < 4; m++)
#pragma unroll
      for (int n = 0; n < 4; n++)
        acc[m][n] = __builtin_amdgcn_mfma_f32_16x16x32_bf16(af[m], bfv[n], acc[m][n], 0, 0, 0);
    __syncthreads();   // drains vmcnt(0): prefetched tile ready; reads of cur done
    cur ^= 1;
  }

  if (MODE == 0) {
    unsigned short* C = (unsigned short*)Cv;
#pragma unroll
    for (int m = 0; m < 4; m++)
#pragma unroll
      for (int n = 0; n < 4; n++)
#pragma unroll
        for (int r = 0; r < 4; r++) {
          int rg = brow + wr * 64 + m * 16 + fq * 4 + r;
          int cg = bcol + wc * 64 + n * 16 + fr;
          C[(size_t)rg * ldc + cg] = f2bf(acc[m][n][r] * scale);
        }
  } else {
    float* C = (float*)Cv + (size_t)b * batchC;
#pragma unroll
    for (int m = 0; m < 4; m++)
#pragma unroll
      for (int n = 0; n < 4; n++)
#pragma unroll
        for (int r = 0; r < 4; r++) {
          int rg = brow + wr * 64 + m * 16 + fq * 4 + r;
          int cg = bcol + wc * 64 + n * 16 + fr;
          C[(size_t)rg * ldc + cg] = acc[m][n][r];
        }
  }
}

// ---------------- scores: compact causal grid + mask bit-prefetch ------
// grid: 1088 blocks (8 batches x 136 lower-triangle 128x128 tiles), XCD-swizzled
template<int F32OUT>
__global__ __launch_bounds__(256) void k_scores(
    const unsigned short* __restrict__ QP,
    const unsigned short* __restrict__ KP,
    void* __restrict__ Sv,
    const int* __restrict__ mask)
{
  int bid0 = blockIdx.x;
  int bid = (bid0 & 7) * 136 + (bid0 >> 3);   // 1088 % 8 == 0: bijective
  const int b = bid / 136;
  int t = bid - b * 136;
  int by = (int)((sqrtf((float)(8 * t + 1)) - 1.0f) * 0.5f);
  if ((by + 1) * (by + 2) / 2 <= t) by++;
  else if (by * (by + 1) / 2 > t) by--;
  const int bx = t - (by * (by + 1)) / 2;     // bx <= by
  const int brow = by * 128, bcol = bx * 128;

  const unsigned short* A  = QP + (size_t)b * (2048 * 1024);
  const unsigned short* Bt = KP + (size_t)b * (2048 * 1024);

  __shared__ unsigned short As[2][128 * 32];
  __shared__ unsigned short Bs[2][128 * 32];

  const int tid = threadIdx.x, wid = tid >> 6, lane = tid & 63;
  const int wr = wid >> 1, wc = wid & 1;
  const int fr = lane & 15, fq = lane >> 4;

  // --- mask prefetch: the 64 elements this lane's epilogue needs -> 64 bits
  const int* mk = mask + (size_t)b * 2048 * 2048;
  unsigned mbits[2];
#pragma unroll
  for (int h = 0; h < 2; h++) {
    int tmp[32];
#pragma unroll
    for (int j = 0; j < 32; j++) {
      int jj = h * 32 + j;
      int m = jj >> 4, n = (jj >> 2) & 3, r = jj & 3;
      int qq = brow + wr * 64 + m * 16 + fq * 4 + r;
      int kk = bcol + wc * 64 + n * 16 + fr;
      tmp[j] = mk[(size_t)qq * 2048 + kk];
    }
    unsigned bv = 0;
#pragma unroll
    for (int j = 0; j < 32; j++) bv |= (tmp[j] ? 1u : 0u) << j;
    mbits[h] = bv;
  }

  f32x4 acc[4][4] = {};
  const int srow = wid * 16 + (lane >> 2);
  const int scol = (lane & 3) * 8;

  auto stage = [&](int buf, int k0) {
    const unsigned short* ga = A + (size_t)(brow + srow) * 1024 + k0 + scol;
    gl16(ga, &As[buf][(wid * 16) * 32]);
    gl16(ga + (size_t)64 * 1024, &As[buf][(64 + wid * 16) * 32]);
    const unsigned short* gb = Bt + (size_t)(bcol + srow) * 1024 + k0 + scol;
    gl16(gb, &Bs[buf][(wid * 16) * 32]);
    gl16(gb + (size_t)64 * 1024, &Bs[buf][(64 + wid * 16) * 32]);
  };

  stage(0, 0);
  __syncthreads();
  int cur = 0;
  for (int t2 = 0; t2 < 32; ++t2) {
    if (t2 + 1 < 32) stage(cur ^ 1, (t2 + 1) * 32);

    bf16x8 af[4], bfv[4];
#pragma unroll
    for (int m = 0; m < 4; m++)
      af[m] = __builtin_bit_cast(bf16x8,
          *(const u16x8*)&As[cur][(wr * 64 + m * 16 + fr) * 32 + fq * 8]);
#pragma unroll
    for (int n = 0; n < 4; n++)
      bfv[n] = __builtin_bit_cast(bf16x8,
          *(const u16x8*)&Bs[cur][(wc * 64 + n * 16 + fr) * 32 + fq * 8]);
#pragma unroll
    for (int m = 0; m < 4; m++)
#pragma unroll
      for (int n = 0; n < 4; n++)
        acc[m][n] = __builtin_amdgcn_mfma_f32_16x16x32_bf16(af[m], bfv[n], acc[m][n], 0, 0, 0);
    __syncthreads();
    cur ^= 1;
  }

  float* Cf = (float*)Sv + (size_t)b * 2048 * 2048;
  unsigned short* Cb = (unsigned short*)Sv + (size_t)b * 2048 * 2048;
#pragma unroll
  for (int m = 0; m < 4; m++)
#pragma unroll
    for (int n = 0; n < 4; n++)
#pragma unroll
      for (int r = 0; r < 4; r++) {
        int jj = (m << 4) | (n << 2) | r;
        int qq = brow + wr * 64 + m * 16 + fq * 4 + r;
        int kk = bcol + wc * 64 + n * 16 + fr;
        float s = acc[m][n][r];
        if (!((mbits[jj >> 5] >> (jj & 31)) & 1u)) s = NEGF;
        if (kk > qq) s = NEGF;
        else if (s == 0.0f) s = NEGF;
        if (F32OUT) Cf[(size_t)qq * 2048 + kk] = s;
        else        Cb[(size_t)qq * 2048 + kk] = f2bf(s);
      }
}

// ---------------- row softmax (one block per row) ----------------
template<bool F32IN>
__global__ __launch_bounds__(256) void k_softmax(const void* __restrict__ Sin,
                                                 unsigned short* __restrict__ P) {
  const int row = blockIdx.x;
  const int qq = row & 2047;
  const int L = ((qq >> 7) + 1) << 7;   // causal tile-rounded row length
  const int tid = threadIdx.x;
  float val[8];
  float mx = -3.0e38f;
  int cnt = 0;
  if (F32IN) {
    const float4* s = (const float4*)((const float*)Sin + (size_t)row * 2048);
    for (int i = tid; i * 4 < L; i += 256) {
      float4 f = s[i];
      val[cnt] = f.x; val[cnt + 1] = f.y; val[cnt + 2] = f.z; val[cnt + 3] = f.w;
      mx = fmaxf(fmaxf(fmaxf(mx, f.x), f.y), fmaxf(f.z, f.w));
      cnt += 4;
    }
  } else {
    const unsigned short* s = (const unsigned short*)Sin + (size_t)row * 2048;
    for (int i = tid; i < L; i += 256) { float f = bf2f(s[i]); val[cnt++] = f; mx = fmaxf(mx, f); }
  }
#pragma unroll
  for (int o = 32; o; o >>= 1) mx = fmaxf(mx, __shfl_xor(mx, o));
  __shared__ float sred[8];
  if ((tid & 63) == 0) sred[tid >> 6] = mx;
  __syncthreads();
  mx = fmaxf(fmaxf(sred[0], sred[1]), fmaxf(sred[2], sred[3]));
  float sum = 0.f;
  for (int j = 0; j < cnt; j++) { val[j] = __expf(val[j] - mx); sum += val[j]; }
#pragma unroll
  for (int o = 32; o; o >>= 1) sum += __shfl_xor(sum, o);
  if ((tid & 63) == 0) sred[4 + (tid >> 6)] = sum;
  __syncthreads();
  sum = (sred[4] + sred[5]) + (sred[6] + sred[7]);
  const float inv = 1.0f / sum;
  unsigned short* p = P + (size_t)row * 2048;
  if (F32IN) {
    int j = 0;
    for (int i = tid; i * 4 < L; i += 256) {
      ushort4 o;
      o.x = f2bf(val[j] * inv); o.y = f2bf(val[j + 1] * inv);
      o.z = f2bf(val[j + 2] * inv); o.w = f2bf(val[j + 3] * inv);
      *(ushort4*)(p + i * 4) = o;
      j += 4;
    }
  } else {
    int j = 0;
    for (int i = tid; i < L; i += 256) p[i] = f2bf(val[j++] * inv);
  }
}

extern "C" void kernel_launch(void* const* d_in, const int* in_sizes, int n_in,
                              void* d_out, int out_size, void* d_ws, size_t ws_size,
                              hipStream_t stream) {
  const float* q   = (const float*)d_in[0];
  const float* k   = (const float*)d_in[1];
  const float* v   = (const float*)d_in[2];
  const int*   msk = (const int*)d_in[3];
  const float* Wq  = (const float*)d_in[4];
  const float* Wk  = (const float*)d_in[5];
  const float* Wv  = (const float*)d_in[6];
  float* out = (float*)d_out;

  char* ws = (char*)d_ws;
  unsigned short* WqT = (unsigned short*)(ws + 0);
  unsigned short* WkT = (unsigned short*)(ws + 2097152);
  unsigned short* WvT = (unsigned short*)(ws + 4194304);
  unsigned short* qp  = (unsigned short*)(ws + 6291456);
  unsigned short* kp  = (unsigned short*)(ws + 39845888);
  unsigned short* vpT = (unsigned short*)(ws + 73400320);
  unsigned short* qbf = (unsigned short*)(ws + 106954752);
  unsigned short* kbf = (unsigned short*)(ws + 140509184);
  unsigned short* vbf = (unsigned short*)(ws + 174063616);
  const bool f32s = ws_size >= 308281344ull;
  float* Sf = (float*)(ws + 106954752);                    // aliases q/k/v bf16 (dead)
  unsigned short* P = f32s ? (unsigned short*)(ws + 241172480)
                           : (unsigned short*)(ws + 106954752);

  dim3 blk(256);
  // 1) conversions
  k_cvt<<<dim3(8192), blk, 0, stream>>>(q, qbf);
  k_cvt<<<dim3(8192), blk, 0, stream>>>(k, kbf);
  k_cvt<<<dim3(8192), blk, 0, stream>>>(v, vbf);
  k_cvt_w<<<dim3(32, 32), blk, 0, stream>>>(Wq, WqT);
  k_cvt_w<<<dim3(32, 32), blk, 0, stream>>>(Wk, WkT);
  k_cvt_w<<<dim3(32, 32), blk, 0, stream>>>(Wv, WvT);

  // 2) projections: qp (scale folded 1/sqrt(1024)), kp, vpT
  k_gemm<0><<<dim3(8, 128, 1), blk, 0, stream>>>(qbf, 1024, 0, WqT, 1024, 0,
                                                 qp, 1024, 0, 1024, 0.03125f);
  k_gemm<0><<<dim3(8, 128, 1), blk, 0, stream>>>(kbf, 1024, 0, WkT, 1024, 0,
                                                 kp, 1024, 0, 1024, 1.0f);
  k_gemm<0><<<dim3(128, 8, 1), blk, 0, stream>>>(WvT, 1024, 0, vbf, 1024, 0,
                                                 vpT, 16384, 0, 1024, 1.0f);

  // 3) scores (compact causal grid, mask prefetched to bits)
  if (f32s)
    k_scores<1><<<dim3(1088), blk, 0, stream>>>(qp, kp, Sf, msk);
  else
    k_scores<0><<<dim3(1088), blk, 0, stream>>>(qp, kp, P, msk);

  // 4) softmax
  if (f32s) k_softmax<true><<<dim3(16384), blk, 0, stream>>>(Sf, P);
  else      k_softmax<false><<<dim3(16384), blk, 0, stream>>>(P, P);

  // 5) PV: out = P x vpT^T, K truncated at diagonal (long blocks first)
  k_gemm<3><<<dim3(8, 16, 8), blk, 0, stream>>>(P, 2048, (size_t)2048 * 2048,
                                                vpT, 16384, (size_t)2048,
                                                out, 1024, (size_t)2048 * 1024,
                                                0, 1.0f);
  (void)in_sizes; (void)n_in; (void)out_size;
}

// Round 4
// 460.667 us; speedup vs baseline: 1.2334x; 1.0412x over previous
//
#include <hip/hip_runtime.h>
#include <math.h>

typedef __bf16 bf16x8 __attribute__((ext_vector_type(8)));
typedef float  f32x4  __attribute__((ext_vector_type(4)));
typedef unsigned short u16x8 __attribute__((ext_vector_type(8)));

#define NEGF (-1e20f)

__device__ __forceinline__ unsigned short f2bf(float f) {
  union { float f; unsigned u; } x; x.f = f;
  unsigned r = x.u + 0x7fffu + ((x.u >> 16) & 1u);
  return (unsigned short)(r >> 16);
}
__device__ __forceinline__ float bf2f(unsigned short h) {
  union { unsigned u; float f; } x; x.u = ((unsigned)h) << 16;
  return x.f;
}

__device__ __forceinline__ void gl16(const void* g, void* l) {
  __builtin_amdgcn_global_load_lds(
      (const __attribute__((address_space(1))) unsigned int*)g,
      (__attribute__((address_space(3))) unsigned int*)l, 16, 0, 0);
}

// ---------------- f32 -> bf16 convert (8 elems/thread) ----------------
__global__ __launch_bounds__(256) void k_cvt(const float* __restrict__ in,
                                             unsigned short* __restrict__ out) {
  size_t i = ((size_t)blockIdx.x * 256 + threadIdx.x) * 8;
  const float4* p = (const float4*)(in + i);
  float4 a = p[0], b = p[1];
  u16x8 o;
  o[0] = f2bf(a.x); o[1] = f2bf(a.y); o[2] = f2bf(a.z); o[3] = f2bf(a.w);
  o[4] = f2bf(b.x); o[5] = f2bf(b.y); o[6] = f2bf(b.z); o[7] = f2bf(b.w);
  *(u16x8*)(out + i) = o;
}

// ---------------- W (1024x1024 f32) -> W^T bf16 ----------------
__global__ __launch_bounds__(256) void k_cvt_w(const float* __restrict__ W,
                                               unsigned short* __restrict__ WT) {
  __shared__ float t[32][33];
  const int tid = threadIdx.x;
  const int tx = tid & 31, ty = tid >> 5;
  const int e0 = blockIdx.y * 32, a0 = blockIdx.x * 32;
#pragma unroll
  for (int i = 0; i < 4; i++) {
    int el = ty + i * 8;
    t[el][tx] = W[(size_t)(e0 + el) * 1024 + a0 + tx];
  }
  __syncthreads();
#pragma unroll
  for (int i = 0; i < 4; i++) {
    int al = ty + i * 8;
    WT[(size_t)(a0 + al) * 1024 + e0 + tx] = f2bf(t[tx][al]);
  }
}

// Pipelined MFMA core shared by all GEMMs:
// 3 LDS buffers, depth-2 prefetch, counted vmcnt, raw barriers,
// XOR chunk swizzle (c ^= row&3) on both stage-source and ds_read.
#define GEMM_PIPELINE(NT_EXPR)                                                   \
  const int nt = (NT_EXPR);                                                      \
  stage(0, 0);                                                                   \
  stage(1, 32);                                                                  \
  int rb = 0, sb = 2;                                                            \
  for (int t = 0; t < nt; ++t) {                                                 \
    if (t + 2 < nt) {                                                            \
      stage(sb, (t + 2) << 5);                                                   \
      asm volatile("s_waitcnt vmcnt(8)" ::: "memory");                           \
    } else if (t + 1 < nt) {                                                     \
      asm volatile("s_waitcnt vmcnt(4)" ::: "memory");                           \
    } else {                                                                     \
      asm volatile("s_waitcnt vmcnt(0)" ::: "memory");                           \
    }                                                                            \
    __builtin_amdgcn_s_barrier();                                                \
    bf16x8 af[4], bfv[4];                                                        \
    _Pragma("unroll")                                                            \
    for (int m = 0; m < 4; m++)                                                  \
      af[m] = __builtin_bit_cast(bf16x8,                                         \
          *(const u16x8*)&As[rb][(wr * 64 + m * 16 + fr) * 32 + (fq ^ (fr & 3)) * 8]); \
    _Pragma("unroll")                                                            \
    for (int n = 0; n < 4; n++)                                                  \
      bfv[n] = __builtin_bit_cast(bf16x8,                                        \
          *(const u16x8*)&Bs[rb][(wc * 64 + n * 16 + fr) * 32 + (fq ^ (fr & 3)) * 8]); \
    _Pragma("unroll")                                                            \
    for (int m = 0; m < 4; m++)                                                  \
      _Pragma("unroll")                                                          \
      for (int n = 0; n < 4; n++)                                                \
        acc[m][n] = __builtin_amdgcn_mfma_f32_16x16x32_bf16(af[m], bfv[n], acc[m][n], 0, 0, 0); \
    asm volatile("s_waitcnt lgkmcnt(0)" ::: "memory");                           \
    __builtin_amdgcn_s_barrier();                                                \
    rb = (rb == 2) ? 0 : rb + 1;                                                 \
    sb = (sb == 2) ? 0 : sb + 1;                                                 \
  }

// ---------------- generic bf16 MFMA GEMM: C = A[M][K] x Bt[N][K]^T ----
// MODE 0: bf16 out with scale (projections), XCD-swizzled grid
// MODE 3: PV, f32 out, K = brow+128 (causal truncation), by reversed
template<int MODE>
__global__ __launch_bounds__(256) void k_gemm(
    const unsigned short* __restrict__ A, int lda, size_t batchA,
    const unsigned short* __restrict__ Bt, int ldb, size_t batchB,
    void* __restrict__ Cv, int ldc, size_t batchC,
    int K, float scale)
{
  int bx, by;
  const int b = blockIdx.z;
  if (MODE == 0) {
    int nwg = gridDim.x * gridDim.y;
    int lin = blockIdx.y * gridDim.x + blockIdx.x;
    int chunk = nwg >> 3;
    int swz = (lin & 7) * chunk + (lin >> 3);
    bx = swz % gridDim.x;
    by = swz / gridDim.x;
  } else {
    bx = blockIdx.x;
    by = (int)(gridDim.y - 1 - blockIdx.y);   // long K first
  }
  const int brow = by * 128, bcol = bx * 128;
  A  += (size_t)b * batchA;
  Bt += (size_t)b * batchB;

  __shared__ unsigned short As[3][128 * 32];
  __shared__ unsigned short Bs[3][128 * 32];

  const int tid = threadIdx.x, wid = tid >> 6, lane = tid & 63;
  const int wr = wid >> 1, wc = wid & 1;
  const int fr = lane & 15, fq = lane >> 4;

  f32x4 acc[4][4] = {};

  const int Keff = (MODE == 3) ? (brow + 128) : K;
  const int srow = wid * 16 + (lane >> 2);
  const int scol = ((lane & 3) ^ (srow & 3)) * 8;   // pre-swizzled source chunk

  auto stage = [&](int buf, int k0) {
    const unsigned short* ga = A + (size_t)(brow + srow) * lda + k0 + scol;
    gl16(ga, &As[buf][(wid * 16) * 32]);
    gl16(ga + (size_t)64 * lda, &As[buf][(64 + wid * 16) * 32]);
    const unsigned short* gb = Bt + (size_t)(bcol + srow) * ldb + k0 + scol;
    gl16(gb, &Bs[buf][(wid * 16) * 32]);
    gl16(gb + (size_t)64 * ldb, &Bs[buf][(64 + wid * 16) * 32]);
  };

  GEMM_PIPELINE(Keff >> 5)

  if (MODE == 0) {
    unsigned short* C = (unsigned short*)Cv;
#pragma unroll
    for (int m = 0; m < 4; m++)
#pragma unroll
      for (int n = 0; n < 4; n++)
#pragma unroll
        for (int r = 0; r < 4; r++) {
          int rg = brow + wr * 64 + m * 16 + fq * 4 + r;
          int cg = bcol + wc * 64 + n * 16 + fr;
          C[(size_t)rg * ldc + cg] = f2bf(acc[m][n][r] * scale);
        }
  } else {
    float* C = (float*)Cv + (size_t)b * batchC;
#pragma unroll
    for (int m = 0; m < 4; m++)
#pragma unroll
      for (int n = 0; n < 4; n++)
#pragma unroll
        for (int r = 0; r < 4; r++) {
          int rg = brow + wr * 64 + m * 16 + fq * 4 + r;
          int cg = bcol + wc * 64 + n * 16 + fr;
          C[(size_t)rg * ldc + cg] = acc[m][n][r];
        }
  }
}

// ---------------- scores: compact causal grid + mask bit-prefetch ------
template<int F32OUT>
__global__ __launch_bounds__(256) void k_scores(
    const unsigned short* __restrict__ QP,
    const unsigned short* __restrict__ KP,
    void* __restrict__ Sv,
    const int* __restrict__ mask)
{
  int bid0 = blockIdx.x;
  int bid = (bid0 & 7) * 136 + (bid0 >> 3);   // 1088 % 8 == 0: bijective
  const int b = bid / 136;
  int t0 = bid - b * 136;
  int by = (int)((sqrtf((float)(8 * t0 + 1)) - 1.0f) * 0.5f);
  if ((by + 1) * (by + 2) / 2 <= t0) by++;
  else if (by * (by + 1) / 2 > t0) by--;
  const int bx = t0 - (by * (by + 1)) / 2;     // bx <= by
  const int brow = by * 128, bcol = bx * 128;

  const unsigned short* A  = QP + (size_t)b * (2048 * 1024);
  const unsigned short* Bt = KP + (size_t)b * (2048 * 1024);

  __shared__ unsigned short As[3][128 * 32];
  __shared__ unsigned short Bs[3][128 * 32];

  const int tid = threadIdx.x, wid = tid >> 6, lane = tid & 63;
  const int wr = wid >> 1, wc = wid & 1;
  const int fr = lane & 15, fq = lane >> 4;

  // mask prefetch: the 64 elements this lane's epilogue needs -> 64 bits
  const int* mk = mask + (size_t)b * 2048 * 2048;
  unsigned mbits[2];
#pragma unroll
  for (int h = 0; h < 2; h++) {
    int tmp[32];
#pragma unroll
    for (int j = 0; j < 32; j++) {
      int jj = h * 32 + j;
      int m = jj >> 4, n = (jj >> 2) & 3, r = jj & 3;
      int qq = brow + wr * 64 + m * 16 + fq * 4 + r;
      int kk = bcol + wc * 64 + n * 16 + fr;
      tmp[j] = mk[(size_t)qq * 2048 + kk];
    }
    unsigned bv = 0;
#pragma unroll
    for (int j = 0; j < 32; j++) bv |= (tmp[j] ? 1u : 0u) << j;
    mbits[h] = bv;
  }

  f32x4 acc[4][4] = {};
  const int srow = wid * 16 + (lane >> 2);
  const int scol = ((lane & 3) ^ (srow & 3)) * 8;

  auto stage = [&](int buf, int k0) {
    const unsigned short* ga = A + (size_t)(brow + srow) * 1024 + k0 + scol;
    gl16(ga, &As[buf][(wid * 16) * 32]);
    gl16(ga + (size_t)64 * 1024, &As[buf][(64 + wid * 16) * 32]);
    const unsigned short* gb = Bt + (size_t)(bcol + srow) * 1024 + k0 + scol;
    gl16(gb, &Bs[buf][(wid * 16) * 32]);
    gl16(gb + (size_t)64 * 1024, &Bs[buf][(64 + wid * 16) * 32]);
  };

  GEMM_PIPELINE(32)

  float* Cf = (float*)Sv + (size_t)b * 2048 * 2048;
  unsigned short* Cb = (unsigned short*)Sv + (size_t)b * 2048 * 2048;
#pragma unroll
  for (int m = 0; m < 4; m++)
#pragma unroll
    for (int n = 0; n < 4; n++)
#pragma unroll
      for (int r = 0; r < 4; r++) {
        int jj = (m << 4) | (n << 2) | r;
        int qq = brow + wr * 64 + m * 16 + fq * 4 + r;
        int kk = bcol + wc * 64 + n * 16 + fr;
        float s = acc[m][n][r];
        if (!((mbits[jj >> 5] >> (jj & 31)) & 1u)) s = NEGF;
        if (kk > qq) s = NEGF;
        else if (s == 0.0f) s = NEGF;
        if (F32OUT) Cf[(size_t)qq * 2048 + kk] = s;
        else        Cb[(size_t)qq * 2048 + kk] = f2bf(s);
      }
}

// ---------------- row softmax (one block per row) ----------------
template<bool F32IN>
__global__ __launch_bounds__(256) void k_softmax(const void* __restrict__ Sin,
                                                 unsigned short* __restrict__ P) {
  const int row = blockIdx.x;
  const int qq = row & 2047;
  const int L = ((qq >> 7) + 1) << 7;   // causal tile-rounded row length
  const int tid = threadIdx.x;
  float val[8];
  float mx = -3.0e38f;
  int cnt = 0;
  if (F32IN) {
    const float4* s = (const float4*)((const float*)Sin + (size_t)row * 2048);
    for (int i = tid; i * 4 < L; i += 256) {
      float4 f = s[i];
      val[cnt] = f.x; val[cnt + 1] = f.y; val[cnt + 2] = f.z; val[cnt + 3] = f.w;
      mx = fmaxf(fmaxf(fmaxf(mx, f.x), f.y), fmaxf(f.z, f.w));
      cnt += 4;
    }
  } else {
    const unsigned short* s = (const unsigned short*)Sin + (size_t)row * 2048;
    for (int i = tid; i < L; i += 256) { float f = bf2f(s[i]); val[cnt++] = f; mx = fmaxf(mx, f); }
  }
#pragma unroll
  for (int o = 32; o; o >>= 1) mx = fmaxf(mx, __shfl_xor(mx, o));
  __shared__ float sred[8];
  if ((tid & 63) == 0) sred[tid >> 6] = mx;
  __syncthreads();
  mx = fmaxf(fmaxf(sred[0], sred[1]), fmaxf(sred[2], sred[3]));
  float sum = 0.f;
  for (int j = 0; j < cnt; j++) { val[j] = __expf(val[j] - mx); sum += val[j]; }
#pragma unroll
  for (int o = 32; o; o >>= 1) sum += __shfl_xor(sum, o);
  if ((tid & 63) == 0) sred[4 + (tid >> 6)] = sum;
  __syncthreads();
  sum = (sred[4] + sred[5]) + (sred[6] + sred[7]);
  const float inv = 1.0f / sum;
  unsigned short* p = P + (size_t)row * 2048;
  if (F32IN) {
    int j = 0;
    for (int i = tid; i * 4 < L; i += 256) {
      ushort4 o;
      o.x = f2bf(val[j] * inv); o.y = f2bf(val[j + 1] * inv);
      o.z = f2bf(val[j + 2] * inv); o.w = f2bf(val[j + 3] * inv);
      *(ushort4*)(p + i * 4) = o;
      j += 4;
    }
  } else {
    int j = 0;
    for (int i = tid; i < L; i += 256) p[i] = f2bf(val[j++] * inv);
  }
}

extern "C" void kernel_launch(void* const* d_in, const int* in_sizes, int n_in,
                              void* d_out, int out_size, void* d_ws, size_t ws_size,
                              hipStream_t stream) {
  const float* q   = (const float*)d_in[0];
  const float* k   = (const float*)d_in[1];
  const float* v   = (const float*)d_in[2];
  const int*   msk = (const int*)d_in[3];
  const float* Wq  = (const float*)d_in[4];
  const float* Wk  = (const float*)d_in[5];
  const float* Wv  = (const float*)d_in[6];
  float* out = (float*)d_out;

  char* ws = (char*)d_ws;
  unsigned short* WqT = (unsigned short*)(ws + 0);
  unsigned short* WkT = (unsigned short*)(ws + 2097152);
  unsigned short* WvT = (unsigned short*)(ws + 4194304);
  unsigned short* qp  = (unsigned short*)(ws + 6291456);
  unsigned short* kp  = (unsigned short*)(ws + 39845888);
  unsigned short* vpT = (unsigned short*)(ws + 73400320);
  unsigned short* qbf = (unsigned short*)(ws + 106954752);
  unsigned short* kbf = (unsigned short*)(ws + 140509184);
  unsigned short* vbf = (unsigned short*)(ws + 174063616);
  const bool f32s = ws_size >= 308281344ull;
  float* Sf = (float*)(ws + 106954752);                    // aliases q/k/v bf16 (dead)
  unsigned short* P = f32s ? (unsigned short*)(ws + 241172480)
                           : (unsigned short*)(ws + 106954752);

  dim3 blk(256);
  // 1) conversions
  k_cvt<<<dim3(8192), blk, 0, stream>>>(q, qbf);
  k_cvt<<<dim3(8192), blk, 0, stream>>>(k, kbf);
  k_cvt<<<dim3(8192), blk, 0, stream>>>(v, vbf);
  k_cvt_w<<<dim3(32, 32), blk, 0, stream>>>(Wq, WqT);
  k_cvt_w<<<dim3(32, 32), blk, 0, stream>>>(Wk, WkT);
  k_cvt_w<<<dim3(32, 32), blk, 0, stream>>>(Wv, WvT);

  // 2) projections: qp (scale folded 1/sqrt(1024)), kp, vpT
  k_gemm<0><<<dim3(8, 128, 1), blk, 0, stream>>>(qbf, 1024, 0, WqT, 1024, 0,
                                                 qp, 1024, 0, 1024, 0.03125f);
  k_gemm<0><<<dim3(8, 128, 1), blk, 0, stream>>>(kbf, 1024, 0, WkT, 1024, 0,
                                                 kp, 1024, 0, 1024, 1.0f);
  k_gemm<0><<<dim3(128, 8, 1), blk, 0, stream>>>(WvT, 1024, 0, vbf, 1024, 0,
                                                 vpT, 16384, 0, 1024, 1.0f);

  // 3) scores (compact causal grid, mask prefetched to bits)
  if (f32s)
    k_scores<1><<<dim3(1088), blk, 0, stream>>>(qp, kp, Sf, msk);
  else
    k_scores<0><<<dim3(1088), blk, 0, stream>>>(qp, kp, P, msk);

  // 4) softmax
  if (f32s) k_softmax<true><<<dim3(16384), blk, 0, stream>>>(Sf, P);
  else      k_softmax<false><<<dim3(16384), blk, 0, stream>>>(P, P);

  // 5) PV: out = P x vpT^T, K truncated at diagonal (long blocks first)
  k_gemm<3><<<dim3(8, 16, 8), blk, 0, stream>>>(P, 2048, (size_t)2048 * 2048,
                                                vpT, 16384, (size_t)2048,
                                                out, 1024, (size_t)2048 * 1024,
                                                0, 1.0f);
  (void)in_sizes; (void)n_in; (void)out_size;
}